// Round 4
// 324.060 us; speedup vs baseline: 1.0047x; 1.0047x over previous
//
#include <hip/hip_runtime.h>
#include <math.h>

// MarginLoss: out[b] = -relu(logits[b][label[b]] - max_{c != label[b]} logits[b][c])
// B=65536, C=1000 fp32. Streaming row-reduction, 262 MB read/launch.
//
// MINIMAL DIFF from the harness-verified round-0 kernel (passed, absmax 0.0):
// identical strided row assignment (r += nwaves), identical while-loop,
// identical in-loop lane==0 store, identical launch shape (2048x256, 8192
// persistent waves, 8 rows each). Only two changes, both targeting the
// software-pipeline waitcnt hazard:
//
//  1. Prefetch is UNCONDITIONAL: `rs = (rn < B) ? rn : 0` index clamp instead
//     of `if (rn < B) { load }`. A load that is conditional in the CFG cannot
//     be awaited with a counted s_waitcnt vmcnt(N) -- the compiler must drain
//     vmcnt(0) at the merge, which also waits for the just-issued next-row
//     loads and serializes every 4 KB row on full HBM latency (~1.7 TB/s
//     observed vs 6.6 TB/s the harness's own fill kernels reach).
//     (The conditional lane==0 STORE is fine: the awaited loads are older
//     than it, so vmcnt(4) is safe on both paths.)
//  2. The tail load (lanes 58..63, v4 index 250..255 past NV=250) is also
//     unconditional: address clamped to an in-range duplicate (cndmask on the
//     address, full-exec load), masked to -inf at CONSUMPTION time inside
//     row_result. Removes the second conditional load from the loop body.
//
// Every iteration now issues exactly the same 4 row loads -> the compiler can
// keep the next row's loads in flight across the current row's reduction.

typedef float v4 __attribute__((ext_vector_type(4)));

constexpr int C  = 1000;
constexpr int NV = 250;  // float4 per row

__device__ __forceinline__ void load_row(const float* __restrict__ row, int lane,
                                         v4& a, v4& b, v4& c, v4& d) {
    const v4* p = (const v4*)row;
    a = __builtin_nontemporal_load(p + lane);
    b = __builtin_nontemporal_load(p + lane + 64);
    c = __builtin_nontemporal_load(p + lane + 128);
    // Unconditional clamped tail load: lanes 58..63 re-read an in-range
    // element of the same row (duplicate), masked to -inf at consumption.
    const int t  = lane + 192;
    const int ti = (t < NV) ? t : lane;
    d = __builtin_nontemporal_load(p + ti);
}

__device__ __forceinline__ float row_result(v4 a, v4 b, v4 c, v4 d,
                                            int lane, int lab) {
    // Mask the duplicate tail values HERE (not at load time) so the prefetched
    // d is not consumed right after issue.
    if (lane + 192 >= NV)
        d = (v4){-INFINITY, -INFINITY, -INFINITY, -INFINITY};

    float m  = -INFINITY;   // max over non-label elements (this lane's slice)
    float lv = -INFINITY;   // label's logit (only the owning lane sets it)
    auto proc = [&](v4 v, int i) {
        const int dd = lab - (i << 2);
        if ((unsigned)dd < 4u) {   // cndmask selects, at most one chunk matches
            lv = (dd == 0) ? v[0] : (dd == 1) ? v[1] : (dd == 2) ? v[2] : v[3];
            if (dd == 0)      v[0] = -INFINITY;
            else if (dd == 1) v[1] = -INFINITY;
            else if (dd == 2) v[2] = -INFINITY;
            else              v[3] = -INFINITY;
        }
        m = fmaxf(m, fmaxf(fmaxf(v[0], v[1]), fmaxf(v[2], v[3])));
    };
    // Tail lanes (i = lane+192 >= 250): dd < 0 so no label hit, d == -inf.
    proc(a, lane); proc(b, lane + 64); proc(c, lane + 128); proc(d, lane + 192);

    const float lvs = __shfl(lv, (lab >> 2) & 63);  // broadcast from owner lane
    #pragma unroll
    for (int off = 32; off > 0; off >>= 1)
        m = fmaxf(m, __shfl_xor(m, off));
    return -fmaxf(lvs - m, 0.0f);  // MARGIN = 0
}

__global__ __launch_bounds__(256) void margin_loss_kernel(
    const float* __restrict__ logits,
    const int* __restrict__ label,
    float* __restrict__ out,
    int B, int nwaves)
{
    const int gwave = (blockIdx.x * blockDim.x + threadIdx.x) >> 6;
    const int lane  = threadIdx.x & 63;

    int r = gwave;
    if (r >= B) return;

    // Prologue: issue row r's loads.
    v4 a, b, c, d;
    load_row(logits + (size_t)r * C, lane, a, b, c, d);
    int lab = label[r];

    while (true) {
        const int rn = r + nwaves;
        // UNCONDITIONAL prefetch; on the final iteration it re-reads row 0,
        // which is L2-hot (every wave does the same) -- negligible traffic.
        const int rs = (rn < B) ? rn : 0;
        v4 an, bn, cn, dn;
        load_row(logits + (size_t)rs * C, lane, an, bn, cn, dn);
        const int labn = label[rs];

        const float res = row_result(a, b, c, d, lane, lab);
        if (lane == 0) out[r] = res;

        if (rn >= B) break;
        a = an; b = bn; c = cn; d = dn; lab = labn;
        r = rn;
    }
}

extern "C" void kernel_launch(void* const* d_in, const int* in_sizes, int n_in,
                              void* d_out, int out_size, void* d_ws, size_t ws_size,
                              hipStream_t stream)
{
    const float* logits = (const float*)d_in[0];
    const int*   label  = (const int*)d_in[1];
    float*       out    = (float*)d_out;

    const int B = out_size;  // 65536

    // Persistent waves: 8192 waves (2048 blocks x 4 waves) -> 8 rows per wave.
    int nwaves = 8192;
    if (nwaves > B) nwaves = B;
    const int rows_per_block = 256 / 64;
    const int grid = (nwaves + rows_per_block - 1) / rows_per_block;
    margin_loss_kernel<<<grid, 256, 0, stream>>>(logits, label, out, B, nwaves);
}